// Round 4
// baseline (848.466 us; speedup 1.0000x reference)
//
#include <hip/hip_runtime.h>
#include <hip/hip_bf16.h>
#include <math.h>

#define NN 50000
#define EE 800000
#define NT (EE / 16)          // 50000 flat 16-edge tiles (exact)

typedef short s8v __attribute__((ext_vector_type(8)));   // 8 x bf16 (4 VGPRs)
typedef float f4v __attribute__((ext_vector_type(4)));   // MFMA C/D

__device__ __forceinline__ short f2bf(float f) {         // fp32 -> bf16 RNE
    unsigned u = __float_as_uint(f);
    u += 0x7fffu + ((u >> 16) & 1u);
    return (short)(u >> 16);
}

// monotone fp32 <-> uint encode for atomicMax-based segment max.
// key 0 (memset) < enc(any float incl -inf) -> "never touched" -> decodes to 0.
__device__ __forceinline__ unsigned enc(float f) {
    unsigned u = __float_as_uint(f);
    return (u & 0x80000000u) ? ~u : (u | 0x80000000u);
}
__device__ __forceinline__ float dec(unsigned k) {
    if (k == 0u) return 0.0f;                            // empty segment -> 0
    unsigned u = (k & 0x80000000u) ? (k & 0x7fffffffu) : ~k;
    return __uint_as_float(u);
}

// mish(x) = x * (e^{2x}+2e^x) / (e^{2x}+2e^x+2); guard large x
__device__ __forceinline__ float mish_fast(float v) {
    float t = __expf(v);
    float s = t * (t + 2.0f);
    float r = v * s * __builtin_amdgcn_rcpf(s + 2.0f);
    return (v > 15.0f) ? v : r;
}

#define MFMA16(a, b, c) __builtin_amdgcn_mfma_f32_16x16x32_bf16(a, b, c, 0, 0, 0)

// ---------------- CSR build (dst-sorted edge list) ----------------

__global__ __launch_bounds__(256) void count_k(const int* __restrict__ ei,
                                               int* __restrict__ cnt) {
    int e = blockIdx.x * 256 + threadIdx.x;
    if (e < EE) atomicAdd(&cnt[ei[EE + e]], 1);   // row 1 = dst
}

#define NBS 196                                    // ceil(NN/256)

__global__ __launch_bounds__(256) void scan_part(const int* __restrict__ cnt,
                                                 int* __restrict__ part) {
    int t = threadIdx.x, i = blockIdx.x * 256 + t;
    __shared__ int ps[256];
    ps[t] = (i < NN) ? cnt[i] : 0;
    __syncthreads();
    for (int off = 128; off > 0; off >>= 1) {
        if (t < off) ps[t] += ps[t + off];
        __syncthreads();
    }
    if (t == 0) part[blockIdx.x] = ps[0];
}

__global__ __launch_bounds__(256) void scan_top(int* __restrict__ part) {
    int t = threadIdx.x;
    int v = (t < NBS) ? part[t] : 0;
    __shared__ int ps[256];
    ps[t] = v;
    __syncthreads();
    for (int off = 1; off < 256; off <<= 1) {
        int u = (t >= off) ? ps[t - off] : 0;
        __syncthreads();
        ps[t] += u;
        __syncthreads();
    }
    if (t < NBS) part[t] = ps[t] - v;              // exclusive
}

__global__ __launch_bounds__(256) void scan_fin(const int* __restrict__ cnt,
                                                const int* __restrict__ part,
                                                int* __restrict__ row_off,
                                                int* __restrict__ cur) {
    int t = threadIdx.x, i = blockIdx.x * 256 + t;
    int v = (i < NN) ? cnt[i] : 0;
    __shared__ int ps[256];
    ps[t] = v;
    __syncthreads();
    for (int off = 1; off < 256; off <<= 1) {
        int u = (t >= off) ? ps[t - off] : 0;
        __syncthreads();
        ps[t] += u;
        __syncthreads();
    }
    int excl = ps[t] - v + part[blockIdx.x];
    if (i < NN) {
        row_off[i] = excl;
        cur[i] = excl;
        if (i == NN - 1) row_off[NN] = excl + v;
    }
}

__global__ __launch_bounds__(256) void scatter_k(const int* __restrict__ ei,
                                                 int* __restrict__ cur,
                                                 int* __restrict__ csr_src,
                                                 int* __restrict__ csr_dst) {
    int e = blockIdx.x * 256 + threadIdx.x;
    if (e < EE) {
        int d = ei[EE + e];
        int p = atomicAdd(&cur[d], 1);
        csr_src[p] = ei[e];
        csr_dst[p] = d;
    }
}

// ---------------- fp32 -> bf16 buffer convert ----------------

__global__ __launch_bounds__(256)
void cvt_bf16(const float* __restrict__ x, unsigned short* __restrict__ xb, int n) {
    int i = blockIdx.x * 256 + threadIdx.x;
    if (i < n) xb[i] = (unsigned short)f2bf(x[i]);
}

// ---------------- a0 = xi @ (W1_top - W1_bot) + b1  (dout=64, MFMA) ----------

__global__ __launch_bounds__(256)
void a0_mfma(const unsigned short* __restrict__ xb, const float* __restrict__ w1,
             const float* __restrict__ b1, float* __restrict__ a0, int nwt) {
    const int lane = threadIdx.x & 63;
    const int wid = blockIdx.x * 4 + (threadIdx.x >> 6);
    const int i = lane & 15, q = lane >> 4;
    s8v wf[4][2];
#pragma unroll
    for (int nb = 0; nb < 4; nb++)
#pragma unroll
        for (int kh = 0; kh < 2; kh++)
#pragma unroll
            for (int j = 0; j < 8; j++) {
                int k = kh * 32 + q * 8 + j, n = nb * 16 + i;
                wf[nb][kh][j] = f2bf(w1[k * 64 + n] - w1[(64 + k) * 64 + n]);
            }
    float bia[4];
#pragma unroll
    for (int nb = 0; nb < 4; nb++) bia[nb] = b1[nb * 16 + i];

    const int ntiles = NN / 16;
    for (int t = wid; t < ntiles; t += nwt) {
        const int row0 = t * 16;
        const unsigned short* xr = xb + (size_t)(row0 + i) * 64;
        s8v af0 = *(const s8v*)(xr + q * 8);
        s8v af1 = *(const s8v*)(xr + 32 + q * 8);
        const int rowq = row0 + q * 4;
#pragma unroll
        for (int nb = 0; nb < 4; nb++) {
            f4v c = {0.f, 0.f, 0.f, 0.f};
            c = MFMA16(af0, wf[nb][0], c);
            c = MFMA16(af1, wf[nb][1], c);
#pragma unroll
            for (int r = 0; r < 4; r++)
                a0[(size_t)(rowq + r) * 64 + nb * 16 + i] = c[r] + bia[nb];
        }
    }
}

// ---------------- a0_8 = xi @ (W1_top - W1_bot) + b1  (dout=8, MFMA) ---------

__global__ __launch_bounds__(256)
void a0_mfma8(const unsigned short* __restrict__ xb, const float* __restrict__ w1,
              const float* __restrict__ b1, float* __restrict__ a0, int nwt) {
    const int lane = threadIdx.x & 63;
    const int wid = blockIdx.x * 4 + (threadIdx.x >> 6);
    const int i = lane & 15, q = lane >> 4;
    s8v wf[2];
#pragma unroll
    for (int kh = 0; kh < 2; kh++)
#pragma unroll
        for (int j = 0; j < 8; j++) {
            int k = kh * 32 + q * 8 + j;
            wf[kh][j] = (i < 8) ? f2bf(w1[k * 8 + i] - w1[(64 + k) * 8 + i]) : (short)0;
        }
    const float bia = (i < 8) ? b1[i] : 0.0f;

    const int ntiles = NN / 16;
    for (int t = wid; t < ntiles; t += nwt) {
        const int row0 = t * 16;
        const unsigned short* xr = xb + (size_t)(row0 + i) * 64;
        s8v af0 = *(const s8v*)(xr + q * 8);
        s8v af1 = *(const s8v*)(xr + 32 + q * 8);
        f4v c = {0.f, 0.f, 0.f, 0.f};
        c = MFMA16(af0, wf[0], c);
        c = MFMA16(af1, wf[1], c);
        if (i < 8) {
            const int rowq = row0 + q * 4;
#pragma unroll
            for (int r = 0; r < 4; r++)
                a0[(size_t)(rowq + r) * 8 + i] = c[r] + bia;
        }
    }
}

// ------- edge-major fused MLP + segmented max, dout=64 -------
// flat 16-edge tiles, 2-stage software pipeline, atomicMax(enc) aggregation.
// NOTE: every lane ALWAYS flushes its tail run at r==3 (d[4] = -1 sentinel):
// atomicMax merging of partial run maxima is commutative, so partial emits are
// safe; skipping them (R3 bug) drops data whenever a run crosses quads.

__global__ __launch_bounds__(256)
void edge_mfma64(const unsigned short* __restrict__ xb, const float* __restrict__ a0,
                 const float* __restrict__ w1, const float* __restrict__ w2,
                 const float* __restrict__ b2,
                 const int* __restrict__ csr_src, const int* __restrict__ csr_dst,
                 unsigned* __restrict__ y, int nwt) {
    __shared__ float uld[4][16 * 68];
    const int lane = threadIdx.x & 63;
    const int wv = threadIdx.x >> 6;
    const int i = lane & 15, q = lane >> 4;
    float* up = &uld[wv][0];

    s8v w1f[4][2], w2f[4][2];
#pragma unroll
    for (int nb = 0; nb < 4; nb++)
#pragma unroll
        for (int kh = 0; kh < 2; kh++)
#pragma unroll
            for (int j = 0; j < 8; j++) {
                int k = kh * 32 + q * 8 + j, n = nb * 16 + i;
                w1f[nb][kh][j] = f2bf(w1[(64 + k) * 64 + n]);
                w2f[nb][kh][j] = f2bf(w2[k * 64 + n]);
            }
    float b2v[4];
#pragma unroll
    for (int nb = 0; nb < 4; nb++) b2v[nb] = b2[nb * 16 + i];

    int t = blockIdx.x * 4 + wv;
    if (t >= NT) return;
    // pipeline preamble: current tile's src + A-fragments, next tile's src
    int src_c = csr_src[t * 16 + i];
    const unsigned short* xr0 = xb + (size_t)src_c * 64;
    s8v af0_c = *(const s8v*)(xr0 + q * 8);
    s8v af1_c = *(const s8v*)(xr0 + 32 + q * 8);
    int t_n = t + nwt;
    int src_n = (t_n < NT) ? csr_src[t_n * 16 + i] : 0;

    while (true) {
        const bool has_n = t_n < NT;
        s8v af0_n = {0,0,0,0,0,0,0,0}, af1_n = {0,0,0,0,0,0,0,0};
        if (has_n) {                                 // issue next gather early
            const unsigned short* xr = xb + (size_t)src_n * 64;
            af0_n = *(const s8v*)(xr + q * 8);
            af1_n = *(const s8v*)(xr + 32 + q * 8);
        }
        int t_nn = t_n + nwt;
        int src_nn = (t_nn < NT) ? csr_src[t_nn * 16 + i] : 0;

        // dst ids for this tile's rows handled by this lane
        const int e0 = t * 16;
        int d[5];
#pragma unroll
        for (int r = 0; r < 4; r++) d[r] = csr_dst[e0 + q * 4 + r];
        d[4] = -1;                                   // sentinel: ALWAYS flush tail

        // GEMM1
        f4v c0 = {0.f, 0.f, 0.f, 0.f}, c1 = c0, c2 = c0, c3 = c0;
        c0 = MFMA16(af0_c, w1f[0][0], c0); c0 = MFMA16(af1_c, w1f[0][1], c0);
        c1 = MFMA16(af0_c, w1f[1][0], c1); c1 = MFMA16(af1_c, w1f[1][1], c1);
        c2 = MFMA16(af0_c, w1f[2][0], c2); c2 = MFMA16(af1_c, w1f[2][1], c2);
        c3 = MFMA16(af0_c, w1f[3][0], c3); c3 = MFMA16(af1_c, w1f[3][1], c3);

        // + a0[dst], mish -> LDS [row][ch], word stride 68
        asm volatile("" ::: "memory");
#pragma unroll
        for (int r = 0; r < 4; r++) {
            const float* ar = a0 + (size_t)d[r] * 64 + i;
            const int ro = (q * 4 + r) * 68 + i;
            up[ro +  0] = mish_fast(c0[r] + ar[ 0]);
            up[ro + 16] = mish_fast(c1[r] + ar[16]);
            up[ro + 32] = mish_fast(c2[r] + ar[32]);
            up[ro + 48] = mish_fast(c3[r] + ar[48]);
        }
        asm volatile("s_waitcnt lgkmcnt(0)" ::: "memory");

        // read back in A-layout, convert bf16
        s8v uf[2];
#pragma unroll
        for (int kh = 0; kh < 2; kh++) {
            const f4v* rp = (const f4v*)(up + i * 68 + kh * 32 + q * 8);
            f4v v0 = rp[0], v1 = rp[1];
            s8v uu;
            uu[0] = f2bf(v0[0]); uu[1] = f2bf(v0[1]);
            uu[2] = f2bf(v0[2]); uu[3] = f2bf(v0[3]);
            uu[4] = f2bf(v1[0]); uu[5] = f2bf(v1[1]);
            uu[6] = f2bf(v1[2]); uu[7] = f2bf(v1[3]);
            uf[kh] = uu;
        }
        asm volatile("" ::: "memory");

        // GEMM2 + within-lane segmented max + atomic merge (partial-safe)
#pragma unroll
        for (int nb = 0; nb < 4; nb++) {
            f4v cc = {0.f, 0.f, 0.f, 0.f};
            cc = MFMA16(uf[0], w2f[nb][0], cc);
            cc = MFMA16(uf[1], w2f[nb][1], cc);
            float vmax = -INFINITY;
#pragma unroll
            for (int r = 0; r < 4; r++) {
                vmax = fmaxf(vmax, cc[r]);
                if (d[r] != d[r + 1]) {
                    atomicMax(&y[(size_t)d[r] * 64 + nb * 16 + i], enc(vmax + b2v[nb]));
                    vmax = -INFINITY;
                }
            }
        }

        if (!has_n) break;
        t = t_n; t_n = t_nn;
        src_n = src_nn;
        af0_c = af0_n; af1_c = af1_n;
    }
}

// ------- edge-major final layer, dout=8 (padded to 16) -------

__global__ __launch_bounds__(256)
void edge_mfma16(const unsigned short* __restrict__ xb, const float* __restrict__ a0,
                 const float* __restrict__ w1, const float* __restrict__ w2,
                 const float* __restrict__ b2,
                 const int* __restrict__ csr_src, const int* __restrict__ csr_dst,
                 unsigned* __restrict__ y8, int nwt) {
    __shared__ float uld[4][16 * 20];
    const int lane = threadIdx.x & 63;
    const int wv = threadIdx.x >> 6;
    const int i = lane & 15, q = lane >> 4;
    float* up = &uld[wv][0];

    s8v w1f[2], w2f;
#pragma unroll
    for (int kh = 0; kh < 2; kh++)
#pragma unroll
        for (int j = 0; j < 8; j++) {
            int k = kh * 32 + q * 8 + j;
            w1f[kh][j] = (i < 8) ? f2bf(w1[(64 + k) * 8 + i]) : (short)0;
        }
#pragma unroll
    for (int j = 0; j < 8; j++)
        w2f[j] = (q == 0 && i < 8) ? f2bf(w2[j * 8 + i]) : (short)0;
    const float b2v = (i < 8) ? b2[i] : 0.0f;

    int t = blockIdx.x * 4 + wv;
    if (t >= NT) return;
    int src_c = csr_src[t * 16 + i];
    const unsigned short* xr0 = xb + (size_t)src_c * 64;
    s8v af0_c = *(const s8v*)(xr0 + q * 8);
    s8v af1_c = *(const s8v*)(xr0 + 32 + q * 8);
    int t_n = t + nwt;
    int src_n = (t_n < NT) ? csr_src[t_n * 16 + i] : 0;

    while (true) {
        const bool has_n = t_n < NT;
        s8v af0_n = {0,0,0,0,0,0,0,0}, af1_n = {0,0,0,0,0,0,0,0};
        if (has_n) {
            const unsigned short* xr = xb + (size_t)src_n * 64;
            af0_n = *(const s8v*)(xr + q * 8);
            af1_n = *(const s8v*)(xr + 32 + q * 8);
        }
        int t_nn = t_n + nwt;
        int src_nn = (t_nn < NT) ? csr_src[t_nn * 16 + i] : 0;

        const int e0 = t * 16;
        int d[5];
#pragma unroll
        for (int r = 0; r < 4; r++) d[r] = csr_dst[e0 + q * 4 + r];
        d[4] = -1;                                   // sentinel: ALWAYS flush tail

        f4v c = {0.f, 0.f, 0.f, 0.f};
        c = MFMA16(af0_c, w1f[0], c);
        c = MFMA16(af1_c, w1f[1], c);

        asm volatile("" ::: "memory");
#pragma unroll
        for (int r = 0; r < 4; r++) {
            float av = (i < 8) ? a0[(size_t)d[r] * 8 + i] : 0.0f;
            up[(q * 4 + r) * 20 + i] = mish_fast(c[r] + av);   // cols 8..15 = 0
        }
        asm volatile("s_waitcnt lgkmcnt(0)" ::: "memory");

        s8v uf = {0,0,0,0,0,0,0,0};
        if (q < 2) {                                   // k = q*8+j < 16
            const f4v* rp = (const f4v*)(up + i * 20 + q * 8);
            f4v v0 = rp[0], v1 = rp[1];
            uf[0] = f2bf(v0[0]); uf[1] = f2bf(v0[1]);
            uf[2] = f2bf(v0[2]); uf[3] = f2bf(v0[3]);
            uf[4] = f2bf(v1[0]); uf[5] = f2bf(v1[1]);
            uf[6] = f2bf(v1[2]); uf[7] = f2bf(v1[3]);
        }
        asm volatile("" ::: "memory");

        f4v cc = {0.f, 0.f, 0.f, 0.f};
        cc = MFMA16(uf, w2f, cc);

        if (i < 8) {
            float vmax = -INFINITY;
#pragma unroll
            for (int r = 0; r < 4; r++) {
                vmax = fmaxf(vmax, cc[r]);
                if (d[r] != d[r + 1]) {
                    atomicMax(&y8[(size_t)d[r] * 8 + i], enc(vmax + b2v));
                    vmax = -INFINITY;
                }
            }
        }

        if (!has_n) break;
        t = t_n; t_n = t_nn;
        src_n = src_nn;
        af0_c = af0_n; af1_c = af1_n;
    }
}

// ---------------- BatchNorm ----------------

__global__ __launch_bounds__(256)
void bn_stats(const unsigned* __restrict__ yk, float* __restrict__ st) {
    const int tid = threadIdx.x;
    const int ch = tid & 63, grp = tid >> 6;
    float s = 0, qq = 0;
    for (int n = blockIdx.x * 4 + grp; n < NN; n += gridDim.x * 4) {
        float v = dec(yk[(size_t)n * 64 + ch]);
        s += v;
        qq = fmaf(v, v, qq);
    }
    __shared__ float ls[256], lq[256];
    ls[tid] = s; lq[tid] = qq;
    __syncthreads();
    if (tid < 64) {
        s  = ls[tid] + ls[tid + 64] + ls[tid + 128] + ls[tid + 192];
        qq = lq[tid] + lq[tid + 64] + lq[tid + 128] + lq[tid + 192];
        atomicAdd(&st[ch], s);
        atomicAdd(&st[64 + ch], qq);
    }
}

// normalize and emit bf16 for the next layer
__global__ __launch_bounds__(256)
void bn_apply(const unsigned* __restrict__ yk, const float* __restrict__ st,
              const float* __restrict__ g, const float* __restrict__ be,
              unsigned short* __restrict__ xbout) {
    int idx = blockIdx.x * 256 + threadIdx.x;
    if (idx >= NN * 64) return;
    int ch = idx & 63;
    float mu  = st[ch] * (1.0f / NN);
    float var = st[64 + ch] * (1.0f / NN) - mu * mu;
    float sc  = rsqrtf(var + 1e-5f) * g[ch];
    float v = (dec(yk[idx]) - mu) * sc + be[ch];
    xbout[idx] = (unsigned short)f2bf(v);
}

__global__ __launch_bounds__(256)
void decode_out(const unsigned* __restrict__ y8, float* __restrict__ out) {
    int idx = blockIdx.x * 256 + threadIdx.x;
    if (idx < NN * 8) out[idx] = dec(y8[idx]);
}

// ---------------- launch ----------------

extern "C" void kernel_launch(void* const* d_in, const int* in_sizes, int n_in,
                              void* d_out, int out_size, void* d_ws, size_t ws_size,
                              hipStream_t stream) {
    const float* x0 = (const float*)d_in[0];
    const int*   ei = (const int*)d_in[1];
    const float* w1[4] = {(const float*)d_in[3],  (const float*)d_in[9],
                          (const float*)d_in[15], (const float*)d_in[21]};
    const float* b1[4] = {(const float*)d_in[4],  (const float*)d_in[10],
                          (const float*)d_in[16], (const float*)d_in[22]};
    const float* w2[4] = {(const float*)d_in[5],  (const float*)d_in[11],
                          (const float*)d_in[17], (const float*)d_in[23]};
    const float* b2[4] = {(const float*)d_in[6],  (const float*)d_in[12],
                          (const float*)d_in[18], (const float*)d_in[24]};
    const float* gg[3] = {(const float*)d_in[7],  (const float*)d_in[13],
                          (const float*)d_in[19]};
    const float* be[3] = {(const float*)d_in[8],  (const float*)d_in[14],
                          (const float*)d_in[20]};

    char* p = (char*)d_ws;
    auto alloc = [&](size_t bytes) -> char* {
        char* r = p;
        p += (bytes + 255) & ~(size_t)255;
        return r;
    };
    int*      cnt     = (int*)alloc((size_t)NN * 4);
    int*      part    = (int*)alloc((size_t)NBS * 4);
    int*      row_off = (int*)alloc((size_t)(NN + 1) * 4);
    int*      cur     = (int*)alloc((size_t)NN * 4);
    int*      csr_s   = (int*)alloc((size_t)EE * 4);
    int*      csr_d   = (int*)alloc((size_t)EE * 4);
    float*    st      = (float*)alloc(3 * 128 * 4);
    float*    a0      = (float*)alloc((size_t)NN * 64 * 4);   // reused for a0_8
    unsigned* y       = (unsigned*)alloc((size_t)NN * 64 * 4);
    unsigned* y8      = (unsigned*)alloc((size_t)NN * 8 * 4);
    unsigned short* xb0 = (unsigned short*)alloc((size_t)NN * 64 * 2); // also xbB
    unsigned short* xbA = (unsigned short*)alloc((size_t)NN * 64 * 2);
    unsigned short* xbB = xb0;

    hipMemsetAsync(cnt, 0, (size_t)NN * 4, stream);
    hipMemsetAsync(st, 0, 3 * 128 * 4, stream);

    count_k<<<(EE + 255) / 256, 256, 0, stream>>>(ei, cnt);
    scan_part<<<NBS, 256, 0, stream>>>(cnt, part);
    scan_top<<<1, 256, 0, stream>>>(part);
    scan_fin<<<NBS, 256, 0, stream>>>(cnt, part, row_off, cur);
    scatter_k<<<(EE + 255) / 256, 256, 0, stream>>>(ei, cur, csr_s, csr_d);
    cvt_bf16<<<(NN * 64 + 255) / 256, 256, 0, stream>>>(x0, xb0, NN * 64);

    const int NBM = 1024;          // edge kernels: 4 waves/block
    const int NWT = NBM * 4;
    const int NBA = 256;
    const int NWA = NBA * 4;

    const unsigned short* xin[3] = {xb0, xbA, xbB};
    unsigned short* xout[3] = {xbA, xbB, xbA};
    for (int l = 0; l < 3; l++) {
        a0_mfma<<<NBA, 256, 0, stream>>>(xin[l], w1[l], b1[l], a0, NWA);
        hipMemsetAsync(y, 0, (size_t)NN * 64 * 4, stream);
        edge_mfma64<<<NBM, 256, 0, stream>>>(xin[l], a0, w1[l], w2[l], b2[l],
                                             csr_s, csr_d, y, NWT);
        bn_stats<<<256, 256, 0, stream>>>(y, st + 128 * l);
        bn_apply<<<(NN * 64 + 255) / 256, 256, 0, stream>>>(y, st + 128 * l,
                                                            gg[l], be[l], xout[l]);
    }

    // layer 3: xbA -> d_out [N,8]
    a0_mfma8<<<NBA, 256, 0, stream>>>(xbA, w1[3], b1[3], a0, NWA);
    hipMemsetAsync(y8, 0, (size_t)NN * 8 * 4, stream);
    edge_mfma16<<<NBM, 256, 0, stream>>>(xbA, a0, w1[3], w2[3], b2[3],
                                         csr_s, csr_d, y8, NWT);
    decode_out<<<(NN * 8 + 255) / 256, 256, 0, stream>>>(y8, (float*)d_out);
}

// Round 5
// 687.669 us; speedup vs baseline: 1.2338x; 1.2338x over previous
//
#include <hip/hip_runtime.h>
#include <hip/hip_bf16.h>
#include <math.h>

#define NN 50000
#define EE 800000
#define NT (EE / 16)          // 50000 flat 16-edge tiles (exact)
#define NBLK 768              // edge kernels: blocks (4 waves each)
#define CHT 17                // contiguous tiles per wave chunk (768*4*17 >= NT)

typedef short s8v __attribute__((ext_vector_type(8)));   // 8 x bf16 (4 VGPRs)
typedef float f4v __attribute__((ext_vector_type(4)));   // MFMA C/D

__device__ __forceinline__ short f2bf(float f) {         // fp32 -> bf16 RNE
    unsigned u = __float_as_uint(f);
    u += 0x7fffu + ((u >> 16) & 1u);
    return (short)(u >> 16);
}

// monotone fp32 <-> uint encode for atomicMax-based segment max.
// key 0 (memset) < enc(any float) -> "never touched" -> decodes to 0.
__device__ __forceinline__ unsigned enc(float f) {
    unsigned u = __float_as_uint(f);
    return (u & 0x80000000u) ? ~u : (u | 0x80000000u);
}
__device__ __forceinline__ float dec(unsigned k) {
    if (k == 0u) return 0.0f;                            // empty segment -> 0
    unsigned u = (k & 0x80000000u) ? (k & 0x7fffffffu) : ~k;
    return __uint_as_float(u);
}

// mish(x) = x * (e^{2x}+2e^x) / (e^{2x}+2e^x+2); guard large x
__device__ __forceinline__ float mish_fast(float v) {
    float t = __expf(v);
    float s = t * (t + 2.0f);
    float r = v * s * __builtin_amdgcn_rcpf(s + 2.0f);
    return (v > 15.0f) ? v : r;
}

#define MFMA16(a, b, c) __builtin_amdgcn_mfma_f32_16x16x32_bf16(a, b, c, 0, 0, 0)

// ---------------- CSR build (dst-sorted edge list) ----------------

__global__ __launch_bounds__(256) void count_k(const int* __restrict__ ei,
                                               int* __restrict__ cnt) {
    int e = blockIdx.x * 256 + threadIdx.x;
    if (e < EE) atomicAdd(&cnt[ei[EE + e]], 1);   // row 1 = dst
}

#define NBS 196                                    // ceil(NN/256)

__global__ __launch_bounds__(256) void scan_part(const int* __restrict__ cnt,
                                                 int* __restrict__ part) {
    int t = threadIdx.x, i = blockIdx.x * 256 + t;
    __shared__ int ps[256];
    ps[t] = (i < NN) ? cnt[i] : 0;
    __syncthreads();
    for (int off = 128; off > 0; off >>= 1) {
        if (t < off) ps[t] += ps[t + off];
        __syncthreads();
    }
    if (t == 0) part[blockIdx.x] = ps[0];
}

__global__ __launch_bounds__(256) void scan_top(int* __restrict__ part) {
    int t = threadIdx.x;
    int v = (t < NBS) ? part[t] : 0;
    __shared__ int ps[256];
    ps[t] = v;
    __syncthreads();
    for (int off = 1; off < 256; off <<= 1) {
        int u = (t >= off) ? ps[t - off] : 0;
        __syncthreads();
        ps[t] += u;
        __syncthreads();
    }
    if (t < NBS) part[t] = ps[t] - v;              // exclusive
}

__global__ __launch_bounds__(256) void scan_fin(const int* __restrict__ cnt,
                                                const int* __restrict__ part,
                                                int* __restrict__ row_off,
                                                int* __restrict__ cur) {
    int t = threadIdx.x, i = blockIdx.x * 256 + t;
    int v = (i < NN) ? cnt[i] : 0;
    __shared__ int ps[256];
    ps[t] = v;
    __syncthreads();
    for (int off = 1; off < 256; off <<= 1) {
        int u = (t >= off) ? ps[t - off] : 0;
        __syncthreads();
        ps[t] += u;
        __syncthreads();
    }
    int excl = ps[t] - v + part[blockIdx.x];
    if (i < NN) {
        row_off[i] = excl;
        cur[i] = excl;
        if (i == NN - 1) row_off[NN] = excl + v;
    }
}

__global__ __launch_bounds__(256) void scatter_k(const int* __restrict__ ei,
                                                 int* __restrict__ cur,
                                                 int* __restrict__ csr_src,
                                                 int* __restrict__ csr_dst) {
    int e = blockIdx.x * 256 + threadIdx.x;
    if (e < EE) {
        int d = ei[EE + e];
        int p = atomicAdd(&cur[d], 1);
        csr_src[p] = ei[e];
        csr_dst[p] = d;
    }
}

// ---------------- fp32 -> bf16 buffer convert ----------------

__global__ __launch_bounds__(256)
void cvt_bf16(const float* __restrict__ x, unsigned short* __restrict__ xb, int n) {
    int i = blockIdx.x * 256 + threadIdx.x;
    if (i < n) xb[i] = (unsigned short)f2bf(x[i]);
}

// -------- a0 = xi @ (W1_top - W1_bot) + b1  (dout=64, MFMA) --------
// output TRANSPOSED within a row: a0[n*64 + i*4 + nb] holds channel nb*16+i,
// so the edge kernel fetches a row's 4 channels as one float4.

__global__ __launch_bounds__(256)
void a0_mfma(const unsigned short* __restrict__ xb, const float* __restrict__ w1,
             const float* __restrict__ b1, float* __restrict__ a0, int nwt) {
    const int lane = threadIdx.x & 63;
    const int wid = blockIdx.x * 4 + (threadIdx.x >> 6);
    const int i = lane & 15, q = lane >> 4;
    s8v wf[4][2];
#pragma unroll
    for (int nb = 0; nb < 4; nb++)
#pragma unroll
        for (int kh = 0; kh < 2; kh++)
#pragma unroll
            for (int j = 0; j < 8; j++) {
                int k = kh * 32 + q * 8 + j, n = nb * 16 + i;
                wf[nb][kh][j] = f2bf(w1[k * 64 + n] - w1[(64 + k) * 64 + n]);
            }
    float bia[4];
#pragma unroll
    for (int nb = 0; nb < 4; nb++) bia[nb] = b1[nb * 16 + i];

    const int ntiles = NN / 16;
    for (int t = wid; t < ntiles; t += nwt) {
        const int row0 = t * 16;
        const unsigned short* xr = xb + (size_t)(row0 + i) * 64;
        s8v af0 = *(const s8v*)(xr + q * 8);
        s8v af1 = *(const s8v*)(xr + 32 + q * 8);
        const int rowq = row0 + q * 4;
#pragma unroll
        for (int nb = 0; nb < 4; nb++) {
            f4v c = {0.f, 0.f, 0.f, 0.f};
            c = MFMA16(af0, wf[nb][0], c);
            c = MFMA16(af1, wf[nb][1], c);
#pragma unroll
            for (int r = 0; r < 4; r++)
                a0[(size_t)(rowq + r) * 64 + i * 4 + nb] = c[r] + bia[nb];
        }
    }
}

// -------- a0_8 = xi @ (W1_top - W1_bot) + b1  (dout=8, MFMA) --------

__global__ __launch_bounds__(256)
void a0_mfma8(const unsigned short* __restrict__ xb, const float* __restrict__ w1,
              const float* __restrict__ b1, float* __restrict__ a0, int nwt) {
    const int lane = threadIdx.x & 63;
    const int wid = blockIdx.x * 4 + (threadIdx.x >> 6);
    const int i = lane & 15, q = lane >> 4;
    s8v wf[2];
#pragma unroll
    for (int kh = 0; kh < 2; kh++)
#pragma unroll
        for (int j = 0; j < 8; j++) {
            int k = kh * 32 + q * 8 + j;
            wf[kh][j] = (i < 8) ? f2bf(w1[k * 8 + i] - w1[(64 + k) * 8 + i]) : (short)0;
        }
    const float bia = (i < 8) ? b1[i] : 0.0f;

    const int ntiles = NN / 16;
    for (int t = wid; t < ntiles; t += nwt) {
        const int row0 = t * 16;
        const unsigned short* xr = xb + (size_t)(row0 + i) * 64;
        s8v af0 = *(const s8v*)(xr + q * 8);
        s8v af1 = *(const s8v*)(xr + 32 + q * 8);
        f4v c = {0.f, 0.f, 0.f, 0.f};
        c = MFMA16(af0, wf[0], c);
        c = MFMA16(af1, wf[1], c);
        if (i < 8) {
            const int rowq = row0 + q * 4;
#pragma unroll
            for (int r = 0; r < 4; r++)
                a0[(size_t)(rowq + r) * 8 + i] = c[r] + bia;
        }
    }
}

// ------- edge-major fused MLP + segmented max, dout=64 -------
// Contiguous CHT-tile chunk per wave. After GEMM2 the C tile round-trips LDS
// in [row][ch] layout; lane=ch scans 16 rows serially carrying a running max
// across tiles, emitting ONE fully-coalesced 256B atomicMax instruction per
// dst-run (~1.1/tile) — vs R4's ~16 masked scattered atomics/tile. The
// run-boundary compares are wave-uniform (no divergence).

__global__ __launch_bounds__(256)
void edge_mfma64(const unsigned short* __restrict__ xb, const float* __restrict__ a0,
                 const float* __restrict__ w1, const float* __restrict__ w2,
                 const float* __restrict__ b2,
                 const int* __restrict__ csr_src, const int* __restrict__ csr_dst,
                 unsigned* __restrict__ y) {
    __shared__ float uld[4][16 * 68];                 // per-wave tile, stride 68
    __shared__ int dseg[4][17];                       // per-wave dst ids + lookahead
    const int lane = threadIdx.x & 63;
    const int wv = threadIdx.x >> 6;
    const int wid = blockIdx.x * 4 + wv;
    const int i = lane & 15, q = lane >> 4;
    float* up = &uld[wv][0];
    int* dsg = &dseg[wv][0];

    s8v w1f[4][2], w2f[4][2];
#pragma unroll
    for (int nb = 0; nb < 4; nb++)
#pragma unroll
        for (int kh = 0; kh < 2; kh++)
#pragma unroll
            for (int j = 0; j < 8; j++) {
                int k = kh * 32 + q * 8 + j, n = nb * 16 + i;
                w1f[nb][kh][j] = f2bf(w1[(64 + k) * 64 + n]);
                w2f[nb][kh][j] = f2bf(w2[k * 64 + n]);
            }
    const float b2c = b2[lane];                       // channel = lane (scan)

    int t = wid * CHT;
    if (t >= NT) return;
    const int tend = (t + CHT < NT) ? (t + CHT) : NT;

    s8v af0_c, af1_c;
    {
        int s0 = csr_src[t * 16 + i];
        const unsigned short* xr = xb + (size_t)s0 * 64;
        af0_c = *(const s8v*)(xr + q * 8);
        af1_c = *(const s8v*)(xr + 32 + q * 8);
    }
    int src_n = (t + 1 < tend) ? csr_src[(t + 1) * 16 + i] : 0;

    float run = -INFINITY;                            // per-channel running max

    for (; t < tend; t++) {
        const bool has_n = (t + 1) < tend;
        s8v af0_n = {0,0,0,0,0,0,0,0}, af1_n = {0,0,0,0,0,0,0,0};
        if (has_n) {                                  // prefetch next tile's rows
            const unsigned short* xr = xb + (size_t)src_n * 64;
            af0_n = *(const s8v*)(xr + q * 8);
            af1_n = *(const s8v*)(xr + 32 + q * 8);
        }
        int src_nn = (t + 2 < tend) ? csr_src[(t + 2) * 16 + i] : 0;

        // cooperative dst-id load (16 rows + 1 lookahead)
        if (lane < 17) {
            int e = t * 16 + lane;
            dsg[lane] = (e < EE) ? csr_dst[e] : -1;
        }
        asm volatile("s_waitcnt lgkmcnt(0)" ::: "memory");

        int dq[4];
#pragma unroll
        for (int r = 0; r < 4; r++) dq[r] = dsg[q * 4 + r];
        f4v a0r[4];                                    // a0T: one float4 per row
#pragma unroll
        for (int r = 0; r < 4; r++)
            a0r[r] = *(const f4v*)(a0 + (size_t)dq[r] * 64 + i * 4);

        // GEMM1
        f4v c0 = {0.f, 0.f, 0.f, 0.f}, c1 = c0, c2 = c0, c3 = c0;
        c0 = MFMA16(af0_c, w1f[0][0], c0); c0 = MFMA16(af1_c, w1f[0][1], c0);
        c1 = MFMA16(af0_c, w1f[1][0], c1); c1 = MFMA16(af1_c, w1f[1][1], c1);
        c2 = MFMA16(af0_c, w1f[2][0], c2); c2 = MFMA16(af1_c, w1f[2][1], c2);
        c3 = MFMA16(af0_c, w1f[3][0], c3); c3 = MFMA16(af1_c, w1f[3][1], c3);

        // + a0[dst], mish -> LDS [row][ch]
        asm volatile("" ::: "memory");
#pragma unroll
        for (int r = 0; r < 4; r++) {
            const int ro = (q * 4 + r) * 68 + i;
            up[ro +  0] = mish_fast(c0[r] + a0r[r][0]);
            up[ro + 16] = mish_fast(c1[r] + a0r[r][1]);
            up[ro + 32] = mish_fast(c2[r] + a0r[r][2]);
            up[ro + 48] = mish_fast(c3[r] + a0r[r][3]);
        }
        asm volatile("s_waitcnt lgkmcnt(0)" ::: "memory");

        // read back in A-layout, convert bf16
        s8v uf[2];
#pragma unroll
        for (int kh = 0; kh < 2; kh++) {
            const f4v* rp = (const f4v*)(up + i * 68 + kh * 32 + q * 8);
            f4v v0 = rp[0], v1 = rp[1];
            s8v uu;
            uu[0] = f2bf(v0[0]); uu[1] = f2bf(v0[1]);
            uu[2] = f2bf(v0[2]); uu[3] = f2bf(v0[3]);
            uu[4] = f2bf(v1[0]); uu[5] = f2bf(v1[1]);
            uu[6] = f2bf(v1[2]); uu[7] = f2bf(v1[3]);
            uf[kh] = uu;
        }
        asm volatile("" ::: "memory");

        // GEMM2
        f4v cc[4];
#pragma unroll
        for (int nb = 0; nb < 4; nb++) {
            f4v c = {0.f, 0.f, 0.f, 0.f};
            c = MFMA16(uf[0], w2f[nb][0], c);
            c = MFMA16(uf[1], w2f[nb][1], c);
            cc[nb] = c;
        }

        // C tile -> LDS [row][ch] (reuse buffer: uf already consumed by MFMA)
#pragma unroll
        for (int nb = 0; nb < 4; nb++)
#pragma unroll
            for (int r = 0; r < 4; r++)
                up[(q * 4 + r) * 68 + nb * 16 + i] = cc[nb][r];
        asm volatile("s_waitcnt lgkmcnt(0)" ::: "memory");

        // serial segmented-max scan; channel = lane; uniform branches
        float v[16];
#pragma unroll
        for (int row = 0; row < 16; row++) v[row] = up[row * 68 + lane];

        int dcur = dsg[0];
#pragma unroll
        for (int row = 0; row < 16; row++) {
            run = fmaxf(run, v[row]);
            int dn = (row < 15) ? dsg[row + 1] : (has_n ? dsg[16] : -1);
            if (dcur != dn) {
                atomicMax(&y[(size_t)dcur * 64 + lane], enc(run + b2c));
                run = -INFINITY;
            }
            dcur = dn;
        }
        asm volatile("s_waitcnt lgkmcnt(0)" ::: "memory");  // scan reads drained

        src_n = src_nn;
        af0_c = af0_n; af1_c = af1_n;
    }
}

// ------- edge-major final layer, dout=8 (padded to 16), same scan scheme ----

__global__ __launch_bounds__(256)
void edge_mfma16(const unsigned short* __restrict__ xb, const float* __restrict__ a0,
                 const float* __restrict__ w1, const float* __restrict__ w2,
                 const float* __restrict__ b2,
                 const int* __restrict__ csr_src, const int* __restrict__ csr_dst,
                 unsigned* __restrict__ y8) {
    __shared__ float uld[4][16 * 20];
    __shared__ int dseg[4][17];
    const int lane = threadIdx.x & 63;
    const int wv = threadIdx.x >> 6;
    const int wid = blockIdx.x * 4 + wv;
    const int i = lane & 15, q = lane >> 4;
    float* up = &uld[wv][0];
    int* dsg = &dseg[wv][0];

    s8v w1f[2], w2f;
#pragma unroll
    for (int kh = 0; kh < 2; kh++)
#pragma unroll
        for (int j = 0; j < 8; j++) {
            int k = kh * 32 + q * 8 + j;
            w1f[kh][j] = (i < 8) ? f2bf(w1[(64 + k) * 8 + i]) : (short)0;
        }
#pragma unroll
    for (int j = 0; j < 8; j++)
        w2f[j] = (q == 0 && i < 8) ? f2bf(w2[j * 8 + i]) : (short)0;
    const float b2c = (lane < 8) ? b2[lane] : 0.0f;

    int t = wid * CHT;
    if (t >= NT) return;
    const int tend = (t + CHT < NT) ? (t + CHT) : NT;

    s8v af0_c, af1_c;
    {
        int s0 = csr_src[t * 16 + i];
        const unsigned short* xr = xb + (size_t)s0 * 64;
        af0_c = *(const s8v*)(xr + q * 8);
        af1_c = *(const s8v*)(xr + 32 + q * 8);
    }
    int src_n = (t + 1 < tend) ? csr_src[(t + 1) * 16 + i] : 0;

    float run = -INFINITY;

    for (; t < tend; t++) {
        const bool has_n = (t + 1) < tend;
        s8v af0_n = {0,0,0,0,0,0,0,0}, af1_n = {0,0,0,0,0,0,0,0};
        if (has_n) {
            const unsigned short* xr = xb + (size_t)src_n * 64;
            af0_n = *(const s8v*)(xr + q * 8);
            af1_n = *(const s8v*)(xr + 32 + q * 8);
        }
        int src_nn = (t + 2 < tend) ? csr_src[(t + 2) * 16 + i] : 0;

        if (lane < 17) {
            int e = t * 16 + lane;
            dsg[lane] = (e < EE) ? csr_dst[e] : -1;
        }
        asm volatile("s_waitcnt lgkmcnt(0)" ::: "memory");

        int dq[4];
#pragma unroll
        for (int r = 0; r < 4; r++) dq[r] = dsg[q * 4 + r];
        float av[4];
#pragma unroll
        for (int r = 0; r < 4; r++)
            av[r] = (i < 8) ? a0[(size_t)dq[r] * 8 + i] : 0.0f;

        f4v c = {0.f, 0.f, 0.f, 0.f};
        c = MFMA16(af0_c, w1f[0], c);
        c = MFMA16(af1_c, w1f[1], c);

        asm volatile("" ::: "memory");
#pragma unroll
        for (int r = 0; r < 4; r++)
            up[(q * 4 + r) * 20 + i] = mish_fast(c[r] + av[r]);   // cols 8..15 = 0
        asm volatile("s_waitcnt lgkmcnt(0)" ::: "memory");

        s8v uf = {0,0,0,0,0,0,0,0};
        if (q < 2) {                                   // k = q*8+j < 16
            const f4v* rp = (const f4v*)(up + i * 20 + q * 8);
            f4v v0 = rp[0], v1 = rp[1];
            uf[0] = f2bf(v0[0]); uf[1] = f2bf(v0[1]);
            uf[2] = f2bf(v0[2]); uf[3] = f2bf(v0[3]);
            uf[4] = f2bf(v1[0]); uf[5] = f2bf(v1[1]);
            uf[6] = f2bf(v1[2]); uf[7] = f2bf(v1[3]);
        }
        asm volatile("" ::: "memory");

        f4v cc = {0.f, 0.f, 0.f, 0.f};
        cc = MFMA16(uf, w2f, cc);

#pragma unroll
        for (int r = 0; r < 4; r++)
            up[(q * 4 + r) * 20 + i] = cc[r];
        asm volatile("s_waitcnt lgkmcnt(0)" ::: "memory");

        float v[16];
#pragma unroll
        for (int row = 0; row < 16; row++) v[row] = up[row * 20 + (lane & 7)];

        int dcur = dsg[0];
#pragma unroll
        for (int row = 0; row < 16; row++) {
            run = fmaxf(run, v[row]);
            int dn = (row < 15) ? dsg[row + 1] : (has_n ? dsg[16] : -1);
            if (dcur != dn) {
                if (lane < 8)
                    atomicMax(&y8[(size_t)dcur * 8 + lane], enc(run + b2c));
                run = -INFINITY;
            }
            dcur = dn;
        }
        asm volatile("s_waitcnt lgkmcnt(0)" ::: "memory");

        src_n = src_nn;
        af0_c = af0_n; af1_c = af1_n;
    }
}

// ---------------- BatchNorm ----------------

__global__ __launch_bounds__(256)
void bn_stats(const unsigned* __restrict__ yk, float* __restrict__ st) {
    const int tid = threadIdx.x;
    const int ch = tid & 63, grp = tid >> 6;
    float s = 0, qq = 0;
    for (int n = blockIdx.x * 4 + grp; n < NN; n += gridDim.x * 4) {
        float v = dec(yk[(size_t)n * 64 + ch]);
        s += v;
        qq = fmaf(v, v, qq);
    }
    __shared__ float ls[256], lq[256];
    ls[tid] = s; lq[tid] = qq;
    __syncthreads();
    if (tid < 64) {
        s  = ls[tid] + ls[tid + 64] + ls[tid + 128] + ls[tid + 192];
        qq = lq[tid] + lq[tid + 64] + lq[tid + 128] + lq[tid + 192];
        atomicAdd(&st[ch], s);
        atomicAdd(&st[64 + ch], qq);
    }
}

// normalize and emit bf16 for the next layer
__global__ __launch_bounds__(256)
void bn_apply(const unsigned* __restrict__ yk, const float* __restrict__ st,
              const float* __restrict__ g, const float* __restrict__ be,
              unsigned short* __restrict__ xbout) {
    int idx = blockIdx.x * 256 + threadIdx.x;
    if (idx >= NN * 64) return;
    int ch = idx & 63;
    float mu  = st[ch] * (1.0f / NN);
    float var = st[64 + ch] * (1.0f / NN) - mu * mu;
    float sc  = rsqrtf(var + 1e-5f) * g[ch];
    float v = (dec(yk[idx]) - mu) * sc + be[ch];
    xbout[idx] = (unsigned short)f2bf(v);
}

__global__ __launch_bounds__(256)
void decode_out(const unsigned* __restrict__ y8, float* __restrict__ out) {
    int idx = blockIdx.x * 256 + threadIdx.x;
    if (idx < NN * 8) out[idx] = dec(y8[idx]);
}

// ---------------- launch ----------------

extern "C" void kernel_launch(void* const* d_in, const int* in_sizes, int n_in,
                              void* d_out, int out_size, void* d_ws, size_t ws_size,
                              hipStream_t stream) {
    const float* x0 = (const float*)d_in[0];
    const int*   ei = (const int*)d_in[1];
    const float* w1[4] = {(const float*)d_in[3],  (const float*)d_in[9],
                          (const float*)d_in[15], (const float*)d_in[21]};
    const float* b1[4] = {(const float*)d_in[4],  (const float*)d_in[10],
                          (const float*)d_in[16], (const float*)d_in[22]};
    const float* w2[4] = {(const float*)d_in[5],  (const float*)d_in[11],
                          (const float*)d_in[17], (const float*)d_in[23]};
    const float* b2[4] = {(const float*)d_in[6],  (const float*)d_in[12],
                          (const float*)d_in[18], (const float*)d_in[24]};
    const float* gg[3] = {(const float*)d_in[7],  (const float*)d_in[13],
                          (const float*)d_in[19]};
    const float* be[3] = {(const float*)d_in[8],  (const float*)d_in[14],
                          (const float*)d_in[20]};

    char* p = (char*)d_ws;
    auto alloc = [&](size_t bytes) -> char* {
        char* r = p;
        p += (bytes + 255) & ~(size_t)255;
        return r;
    };
    int*      cnt     = (int*)alloc((size_t)NN * 4);
    int*      part    = (int*)alloc((size_t)NBS * 4);
    int*      row_off = (int*)alloc((size_t)(NN + 1) * 4);
    int*      cur     = (int*)alloc((size_t)NN * 4);
    int*      csr_s   = (int*)alloc((size_t)EE * 4);
    int*      csr_d   = (int*)alloc((size_t)EE * 4);
    float*    st      = (float*)alloc(3 * 128 * 4);
    float*    a0      = (float*)alloc((size_t)NN * 64 * 4);   // reused for a0_8
    unsigned* y       = (unsigned*)alloc((size_t)NN * 64 * 4);
    unsigned* y8      = (unsigned*)alloc((size_t)NN * 8 * 4);
    unsigned short* xb0 = (unsigned short*)alloc((size_t)NN * 64 * 2); // also xbB
    unsigned short* xbA = (unsigned short*)alloc((size_t)NN * 64 * 2);
    unsigned short* xbB = xb0;

    hipMemsetAsync(cnt, 0, (size_t)NN * 4, stream);
    hipMemsetAsync(st, 0, 3 * 128 * 4, stream);

    count_k<<<(EE + 255) / 256, 256, 0, stream>>>(ei, cnt);
    scan_part<<<NBS, 256, 0, stream>>>(cnt, part);
    scan_top<<<1, 256, 0, stream>>>(part);
    scan_fin<<<NBS, 256, 0, stream>>>(cnt, part, row_off, cur);
    scatter_k<<<(EE + 255) / 256, 256, 0, stream>>>(ei, cur, csr_s, csr_d);
    cvt_bf16<<<(NN * 64 + 255) / 256, 256, 0, stream>>>(x0, xb0, NN * 64);

    const int NBA = 256;
    const int NWA = NBA * 4;

    const unsigned short* xin[3] = {xb0, xbA, xbB};
    unsigned short* xout[3] = {xbA, xbB, xbA};
    for (int l = 0; l < 3; l++) {
        a0_mfma<<<NBA, 256, 0, stream>>>(xin[l], w1[l], b1[l], a0, NWA);
        hipMemsetAsync(y, 0, (size_t)NN * 64 * 4, stream);
        edge_mfma64<<<NBLK, 256, 0, stream>>>(xin[l], a0, w1[l], w2[l], b2[l],
                                              csr_s, csr_d, y);
        bn_stats<<<256, 256, 0, stream>>>(y, st + 128 * l);
        bn_apply<<<(NN * 64 + 255) / 256, 256, 0, stream>>>(y, st + 128 * l,
                                                            gg[l], be[l], xout[l]);
    }

    // layer 3: xbA -> d_out [N,8]
    a0_mfma8<<<NBA, 256, 0, stream>>>(xbA, w1[3], b1[3], a0, NWA);
    hipMemsetAsync(y8, 0, (size_t)NN * 8 * 4, stream);
    edge_mfma16<<<NBLK, 256, 0, stream>>>(xbA, a0, w1[3], w2[3], b2[3],
                                          csr_s, csr_d, y8);
    decode_out<<<(NN * 8 + 255) / 256, 256, 0, stream>>>(y8, (float*)d_out);
}

// Round 6
// 588.041 us; speedup vs baseline: 1.4429x; 1.1694x over previous
//
#include <hip/hip_runtime.h>
#include <hip/hip_bf16.h>
#include <math.h>

#define NN 50000
#define EE 800000
#define NT (EE / 16)          // 50000 flat 16-edge tiles (exact)
#define NBLK 1024             // edge kernels: blocks (4 waves each) = 4/CU resident
#define CHT 13                // contiguous tiles per wave chunk (1024*4*13 >= NT)

typedef short s8v __attribute__((ext_vector_type(8)));   // 8 x bf16 (4 VGPRs)
typedef float f4v __attribute__((ext_vector_type(4)));   // MFMA C/D

__device__ __forceinline__ short f2bf(float f) {         // fp32 -> bf16 RNE
    unsigned u = __float_as_uint(f);
    u += 0x7fffu + ((u >> 16) & 1u);
    return (short)(u >> 16);
}

// monotone fp32 <-> uint encode for atomicMax-based segment max.
// key 0 (memset) < enc(any float) -> "never touched" -> decodes to 0.
__device__ __forceinline__ unsigned enc(float f) {
    unsigned u = __float_as_uint(f);
    return (u & 0x80000000u) ? ~u : (u | 0x80000000u);
}
__device__ __forceinline__ float dec(unsigned k) {
    if (k == 0u) return 0.0f;                            // empty segment -> 0
    unsigned u = (k & 0x80000000u) ? (k & 0x7fffffffu) : ~k;
    return __uint_as_float(u);
}

// mish(x) = x * (e^{2x}+2e^x) / (e^{2x}+2e^x+2); guard large x
__device__ __forceinline__ float mish_fast(float v) {
    float t = __expf(v);
    float s = t * (t + 2.0f);
    float r = v * s * __builtin_amdgcn_rcpf(s + 2.0f);
    return (v > 15.0f) ? v : r;
}

#define MFMA16(a, b, c) __builtin_amdgcn_mfma_f32_16x16x32_bf16(a, b, c, 0, 0, 0)

// ---------------- CSR build (dst-sorted edge list) ----------------

__global__ __launch_bounds__(256) void count_k(const int* __restrict__ ei,
                                               int* __restrict__ cnt) {
    int e = blockIdx.x * 256 + threadIdx.x;
    if (e < EE) atomicAdd(&cnt[ei[EE + e]], 1);   // row 1 = dst
}

#define NBS 196                                    // ceil(NN/256)

__global__ __launch_bounds__(256) void scan_part(const int* __restrict__ cnt,
                                                 int* __restrict__ part) {
    int t = threadIdx.x, i = blockIdx.x * 256 + t;
    __shared__ int ps[256];
    ps[t] = (i < NN) ? cnt[i] : 0;
    __syncthreads();
    for (int off = 128; off > 0; off >>= 1) {
        if (t < off) ps[t] += ps[t + off];
        __syncthreads();
    }
    if (t == 0) part[blockIdx.x] = ps[0];
}

__global__ __launch_bounds__(256) void scan_top(int* __restrict__ part) {
    int t = threadIdx.x;
    int v = (t < NBS) ? part[t] : 0;
    __shared__ int ps[256];
    ps[t] = v;
    __syncthreads();
    for (int off = 1; off < 256; off <<= 1) {
        int u = (t >= off) ? ps[t - off] : 0;
        __syncthreads();
        ps[t] += u;
        __syncthreads();
    }
    if (t < NBS) part[t] = ps[t] - v;              // exclusive
}

__global__ __launch_bounds__(256) void scan_fin(const int* __restrict__ cnt,
                                                const int* __restrict__ part,
                                                int* __restrict__ row_off,
                                                int* __restrict__ cur) {
    int t = threadIdx.x, i = blockIdx.x * 256 + t;
    int v = (i < NN) ? cnt[i] : 0;
    __shared__ int ps[256];
    ps[t] = v;
    __syncthreads();
    for (int off = 1; off < 256; off <<= 1) {
        int u = (t >= off) ? ps[t - off] : 0;
        __syncthreads();
        ps[t] += u;
        __syncthreads();
    }
    int excl = ps[t] - v + part[blockIdx.x];
    if (i < NN) {
        row_off[i] = excl;
        cur[i] = excl;
        if (i == NN - 1) row_off[NN] = excl + v;
    }
}

__global__ __launch_bounds__(256) void scatter_k(const int* __restrict__ ei,
                                                 int* __restrict__ cur,
                                                 int* __restrict__ csr_src,
                                                 int* __restrict__ csr_dst) {
    int e = blockIdx.x * 256 + threadIdx.x;
    if (e < EE) {
        int d = ei[EE + e];
        int p = atomicAdd(&cur[d], 1);
        csr_src[p] = ei[e];
        csr_dst[p] = d;
    }
}

// ---------------- fp32 -> bf16 buffer convert ----------------

__global__ __launch_bounds__(256)
void cvt_bf16(const float* __restrict__ x, unsigned short* __restrict__ xb, int n) {
    int i = blockIdx.x * 256 + threadIdx.x;
    if (i < n) xb[i] = (unsigned short)f2bf(x[i]);
}

// -------- a0 = xi @ (W1_top - W1_bot) + b1  (dout=64, MFMA) --------
// output TRANSPOSED within a row: a0[n*64 + i*4 + nb] holds channel nb*16+i,
// so the edge kernel fetches a row's 4 channels as one float4.

__global__ __launch_bounds__(256)
void a0_mfma(const unsigned short* __restrict__ xb, const float* __restrict__ w1,
             const float* __restrict__ b1, float* __restrict__ a0, int nwt) {
    const int lane = threadIdx.x & 63;
    const int wid = blockIdx.x * 4 + (threadIdx.x >> 6);
    const int i = lane & 15, q = lane >> 4;
    s8v wf[4][2];
#pragma unroll
    for (int nb = 0; nb < 4; nb++)
#pragma unroll
        for (int kh = 0; kh < 2; kh++)
#pragma unroll
            for (int j = 0; j < 8; j++) {
                int k = kh * 32 + q * 8 + j, n = nb * 16 + i;
                wf[nb][kh][j] = f2bf(w1[k * 64 + n] - w1[(64 + k) * 64 + n]);
            }
    float bia[4];
#pragma unroll
    for (int nb = 0; nb < 4; nb++) bia[nb] = b1[nb * 16 + i];

    const int ntiles = NN / 16;
    for (int t = wid; t < ntiles; t += nwt) {
        const int row0 = t * 16;
        const unsigned short* xr = xb + (size_t)(row0 + i) * 64;
        s8v af0 = *(const s8v*)(xr + q * 8);
        s8v af1 = *(const s8v*)(xr + 32 + q * 8);
        const int rowq = row0 + q * 4;
#pragma unroll
        for (int nb = 0; nb < 4; nb++) {
            f4v c = {0.f, 0.f, 0.f, 0.f};
            c = MFMA16(af0, wf[nb][0], c);
            c = MFMA16(af1, wf[nb][1], c);
#pragma unroll
            for (int r = 0; r < 4; r++)
                a0[(size_t)(rowq + r) * 64 + i * 4 + nb] = c[r] + bia[nb];
        }
    }
}

// -------- a0_8 = xi @ (W1_top - W1_bot) + b1  (dout=8, MFMA) --------

__global__ __launch_bounds__(256)
void a0_mfma8(const unsigned short* __restrict__ xb, const float* __restrict__ w1,
              const float* __restrict__ b1, float* __restrict__ a0, int nwt) {
    const int lane = threadIdx.x & 63;
    const int wid = blockIdx.x * 4 + (threadIdx.x >> 6);
    const int i = lane & 15, q = lane >> 4;
    s8v wf[2];
#pragma unroll
    for (int kh = 0; kh < 2; kh++)
#pragma unroll
        for (int j = 0; j < 8; j++) {
            int k = kh * 32 + q * 8 + j;
            wf[kh][j] = (i < 8) ? f2bf(w1[k * 8 + i] - w1[(64 + k) * 8 + i]) : (short)0;
        }
    const float bia = (i < 8) ? b1[i] : 0.0f;

    const int ntiles = NN / 16;
    for (int t = wid; t < ntiles; t += nwt) {
        const int row0 = t * 16;
        const unsigned short* xr = xb + (size_t)(row0 + i) * 64;
        s8v af0 = *(const s8v*)(xr + q * 8);
        s8v af1 = *(const s8v*)(xr + 32 + q * 8);
        f4v c = {0.f, 0.f, 0.f, 0.f};
        c = MFMA16(af0, wf[0], c);
        c = MFMA16(af1, wf[1], c);
        if (i < 8) {
            const int rowq = row0 + q * 4;
#pragma unroll
            for (int r = 0; r < 4; r++)
                a0[(size_t)(rowq + r) * 8 + i] = c[r] + bia;
        }
    }
}

// ------- edge-major fused MLP + segmented max, dout=64 -------
// Contiguous CHT-tile chunk per wave. Latency surgery vs R5:
//  * dseg double-buffered: tile t+1's dst ids prefetched at top of tile t,
//    drained by t's mid-iteration lgkmcnt(0) -> no top-of-loop wait.
//  * a0 gathers issued one tile ahead (after wait#2, when next dsg visible).
//  * af fragments prefetched one tile ahead (as before).
// Critical path per tile is now GEMM1 -> mish -> LDS -> GEMM2 -> LDS -> scan.

__global__ __launch_bounds__(256)
void edge_mfma64(const unsigned short* __restrict__ xb, const float* __restrict__ a0,
                 const float* __restrict__ w1, const float* __restrict__ w2,
                 const float* __restrict__ b2,
                 const int* __restrict__ csr_src, const int* __restrict__ csr_dst,
                 unsigned* __restrict__ y) {
    __shared__ float uld[4][16 * 68];                 // per-wave tile, stride 68
    __shared__ int dseg[4][2][20];                    // per-wave dst ids, dbuf
    const int lane = threadIdx.x & 63;
    const int wv = threadIdx.x >> 6;
    const int wid = blockIdx.x * 4 + wv;
    const int i = lane & 15, q = lane >> 4;
    float* up = &uld[wv][0];

    s8v w1f[4][2], w2f[4][2];
#pragma unroll
    for (int nb = 0; nb < 4; nb++)
#pragma unroll
        for (int kh = 0; kh < 2; kh++)
#pragma unroll
            for (int j = 0; j < 8; j++) {
                int k = kh * 32 + q * 8 + j, n = nb * 16 + i;
                w1f[nb][kh][j] = f2bf(w1[(64 + k) * 64 + n]);
                w2f[nb][kh][j] = f2bf(w2[k * 64 + n]);
            }
    const float b2c = b2[lane];                       // channel = lane (scan)

    int t = wid * CHT;
    if (t >= NT) return;
    const int tend = (t + CHT < NT) ? (t + CHT) : NT;

    // ---- preamble: tile t's dsg, af, dq, a0r all resolved up front ----
    s8v af0_c, af1_c;
    {
        int s0 = csr_src[t * 16 + i];
        const unsigned short* xr = xb + (size_t)s0 * 64;
        af0_c = *(const s8v*)(xr + q * 8);
        af1_c = *(const s8v*)(xr + 32 + q * 8);
    }
    int src_n = (t + 1 < tend) ? csr_src[(t + 1) * 16 + i] : 0;
    if (lane < 17) {
        int e = t * 16 + lane;
        dseg[wv][t & 1][lane] = (e < EE) ? csr_dst[e] : -1;
    }
    asm volatile("s_waitcnt lgkmcnt(0)" ::: "memory");
    int dq_c[4];
#pragma unroll
    for (int r = 0; r < 4; r++) dq_c[r] = dseg[wv][t & 1][q * 4 + r];
    f4v a0r_c[4];
#pragma unroll
    for (int r = 0; r < 4; r++)
        a0r_c[r] = *(const f4v*)(a0 + (size_t)dq_c[r] * 64 + i * 4);

    float run = -INFINITY;                            // per-channel running max

    for (; t < tend; t++) {
        const bool has_n = (t + 1) < tend;
        int* dsg = &dseg[wv][t & 1][0];
        int* dsg_n = &dseg[wv][(t + 1) & 1][0];

        // prefetch next tile's dst ids (LDS write; drains at wait#2 below)
        if (has_n && lane < 17) {
            int e = (t + 1) * 16 + lane;
            dsg_n[lane] = (e < EE) ? csr_dst[e] : -1;
        }
        // prefetch next tile's A fragments
        s8v af0_n = {0,0,0,0,0,0,0,0}, af1_n = {0,0,0,0,0,0,0,0};
        if (has_n) {
            const unsigned short* xr = xb + (size_t)src_n * 64;
            af0_n = *(const s8v*)(xr + q * 8);
            af1_n = *(const s8v*)(xr + 32 + q * 8);
        }
        int src_nn = (t + 2 < tend) ? csr_src[(t + 2) * 16 + i] : 0;

        // GEMM1
        f4v c0 = {0.f, 0.f, 0.f, 0.f}, c1 = c0, c2 = c0, c3 = c0;
        c0 = MFMA16(af0_c, w1f[0][0], c0); c0 = MFMA16(af1_c, w1f[0][1], c0);
        c1 = MFMA16(af0_c, w1f[1][0], c1); c1 = MFMA16(af1_c, w1f[1][1], c1);
        c2 = MFMA16(af0_c, w1f[2][0], c2); c2 = MFMA16(af1_c, w1f[2][1], c2);
        c3 = MFMA16(af0_c, w1f[3][0], c3); c3 = MFMA16(af1_c, w1f[3][1], c3);

        // + a0[dst] (prefetched), mish -> LDS [row][ch]
        asm volatile("" ::: "memory");
#pragma unroll
        for (int r = 0; r < 4; r++) {
            const int ro = (q * 4 + r) * 68 + i;
            up[ro +  0] = mish_fast(c0[r] + a0r_c[r][0]);
            up[ro + 16] = mish_fast(c1[r] + a0r_c[r][1]);
            up[ro + 32] = mish_fast(c2[r] + a0r_c[r][2]);
            up[ro + 48] = mish_fast(c3[r] + a0r_c[r][3]);
        }
        asm volatile("s_waitcnt lgkmcnt(0)" ::: "memory");   // wait#2

        // next tile's dsg is visible now -> issue next a0 gathers
        int dq_n[4];
        f4v a0r_n[4];
        if (has_n) {
#pragma unroll
            for (int r = 0; r < 4; r++) dq_n[r] = dsg_n[q * 4 + r];
#pragma unroll
            for (int r = 0; r < 4; r++)
                a0r_n[r] = *(const f4v*)(a0 + (size_t)dq_n[r] * 64 + i * 4);
        }

        // read back u in A-layout, convert bf16
        s8v uf[2];
#pragma unroll
        for (int kh = 0; kh < 2; kh++) {
            const f4v* rp = (const f4v*)(up + i * 68 + kh * 32 + q * 8);
            f4v v0 = rp[0], v1 = rp[1];
            s8v uu;
            uu[0] = f2bf(v0[0]); uu[1] = f2bf(v0[1]);
            uu[2] = f2bf(v0[2]); uu[3] = f2bf(v0[3]);
            uu[4] = f2bf(v1[0]); uu[5] = f2bf(v1[1]);
            uu[6] = f2bf(v1[2]); uu[7] = f2bf(v1[3]);
            uf[kh] = uu;
        }
        asm volatile("" ::: "memory");

        // GEMM2
        f4v cc[4];
#pragma unroll
        for (int nb = 0; nb < 4; nb++) {
            f4v c = {0.f, 0.f, 0.f, 0.f};
            c = MFMA16(uf[0], w2f[nb][0], c);
            c = MFMA16(uf[1], w2f[nb][1], c);
            cc[nb] = c;
        }

        // C tile -> LDS [row][ch]
#pragma unroll
        for (int nb = 0; nb < 4; nb++)
#pragma unroll
            for (int r = 0; r < 4; r++)
                up[(q * 4 + r) * 68 + nb * 16 + i] = cc[nb][r];
        asm volatile("s_waitcnt lgkmcnt(0)" ::: "memory");   // wait#3

        // serial segmented-max scan; channel = lane; uniform branches
        float v[16];
#pragma unroll
        for (int row = 0; row < 16; row++) v[row] = up[row * 68 + lane];

        int dcur = dsg[0];
#pragma unroll
        for (int row = 0; row < 16; row++) {
            run = fmaxf(run, v[row]);
            int dn = (row < 15) ? dsg[row + 1] : (has_n ? dsg[16] : -1);
            if (dcur != dn) {
                atomicMax(&y[(size_t)dcur * 64 + lane], enc(run + b2c));
                run = -INFINITY;
            }
            dcur = dn;
        }
        asm volatile("s_waitcnt lgkmcnt(0)" ::: "memory");  // WAR guard

        src_n = src_nn;
        af0_c = af0_n; af1_c = af1_n;
#pragma unroll
        for (int r = 0; r < 4; r++) a0r_c[r] = a0r_n[r];
    }
}

// ------- edge-major final layer, dout=8 (padded to 16), same scheme ----

__global__ __launch_bounds__(256)
void edge_mfma16(const unsigned short* __restrict__ xb, const float* __restrict__ a0,
                 const float* __restrict__ w1, const float* __restrict__ w2,
                 const float* __restrict__ b2,
                 const int* __restrict__ csr_src, const int* __restrict__ csr_dst,
                 unsigned* __restrict__ y8) {
    __shared__ float uld[4][16 * 20];
    __shared__ int dseg[4][2][20];
    const int lane = threadIdx.x & 63;
    const int wv = threadIdx.x >> 6;
    const int wid = blockIdx.x * 4 + wv;
    const int i = lane & 15, q = lane >> 4;
    float* up = &uld[wv][0];

    s8v w1f[2], w2f;
#pragma unroll
    for (int kh = 0; kh < 2; kh++)
#pragma unroll
        for (int j = 0; j < 8; j++) {
            int k = kh * 32 + q * 8 + j;
            w1f[kh][j] = (i < 8) ? f2bf(w1[(64 + k) * 8 + i]) : (short)0;
        }
#pragma unroll
    for (int j = 0; j < 8; j++)
        w2f[j] = (q == 0 && i < 8) ? f2bf(w2[j * 8 + i]) : (short)0;
    const float b2c = (lane < 8) ? b2[lane] : 0.0f;

    int t = wid * CHT;
    if (t >= NT) return;
    const int tend = (t + CHT < NT) ? (t + CHT) : NT;

    s8v af0_c, af1_c;
    {
        int s0 = csr_src[t * 16 + i];
        const unsigned short* xr = xb + (size_t)s0 * 64;
        af0_c = *(const s8v*)(xr + q * 8);
        af1_c = *(const s8v*)(xr + 32 + q * 8);
    }
    int src_n = (t + 1 < tend) ? csr_src[(t + 1) * 16 + i] : 0;
    if (lane < 17) {
        int e = t * 16 + lane;
        dseg[wv][t & 1][lane] = (e < EE) ? csr_dst[e] : -1;
    }
    asm volatile("s_waitcnt lgkmcnt(0)" ::: "memory");
    int dq_c[4];
#pragma unroll
    for (int r = 0; r < 4; r++) dq_c[r] = dseg[wv][t & 1][q * 4 + r];
    float av_c[4];
#pragma unroll
    for (int r = 0; r < 4; r++)
        av_c[r] = (i < 8) ? a0[(size_t)dq_c[r] * 8 + i] : 0.0f;

    float run = -INFINITY;

    for (; t < tend; t++) {
        const bool has_n = (t + 1) < tend;
        int* dsg = &dseg[wv][t & 1][0];
        int* dsg_n = &dseg[wv][(t + 1) & 1][0];

        if (has_n && lane < 17) {
            int e = (t + 1) * 16 + lane;
            dsg_n[lane] = (e < EE) ? csr_dst[e] : -1;
        }
        s8v af0_n = {0,0,0,0,0,0,0,0}, af1_n = {0,0,0,0,0,0,0,0};
        if (has_n) {
            const unsigned short* xr = xb + (size_t)src_n * 64;
            af0_n = *(const s8v*)(xr + q * 8);
            af1_n = *(const s8v*)(xr + 32 + q * 8);
        }
        int src_nn = (t + 2 < tend) ? csr_src[(t + 2) * 16 + i] : 0;

        f4v c = {0.f, 0.f, 0.f, 0.f};
        c = MFMA16(af0_c, w1f[0], c);
        c = MFMA16(af1_c, w1f[1], c);

        asm volatile("" ::: "memory");
#pragma unroll
        for (int r = 0; r < 4; r++)
            up[(q * 4 + r) * 20 + i] = mish_fast(c[r] + av_c[r]);   // cols 8..15 = 0
        asm volatile("s_waitcnt lgkmcnt(0)" ::: "memory");           // wait#2

        int dq_n[4];
        float av_n[4] = {0, 0, 0, 0};
        if (has_n) {
#pragma unroll
            for (int r = 0; r < 4; r++) dq_n[r] = dsg_n[q * 4 + r];
#pragma unroll
            for (int r = 0; r < 4; r++)
                av_n[r] = (i < 8) ? a0[(size_t)dq_n[r] * 8 + i] : 0.0f;
        }

        s8v uf = {0,0,0,0,0,0,0,0};
        if (q < 2) {                                   // k = q*8+j < 16
            const f4v* rp = (const f4v*)(up + i * 20 + q * 8);
            f4v v0 = rp[0], v1 = rp[1];
            uf[0] = f2bf(v0[0]); uf[1] = f2bf(v0[1]);
            uf[2] = f2bf(v0[2]); uf[3] = f2bf(v0[3]);
            uf[4] = f2bf(v1[0]); uf[5] = f2bf(v1[1]);
            uf[6] = f2bf(v1[2]); uf[7] = f2bf(v1[3]);
        }
        asm volatile("" ::: "memory");

        f4v cc = {0.f, 0.f, 0.f, 0.f};
        cc = MFMA16(uf, w2f, cc);

#pragma unroll
        for (int r = 0; r < 4; r++)
            up[(q * 4 + r) * 20 + i] = cc[r];
        asm volatile("s_waitcnt lgkmcnt(0)" ::: "memory");           // wait#3

        float v[16];
#pragma unroll
        for (int row = 0; row < 16; row++) v[row] = up[row * 20 + (lane & 7)];

        int dcur = dsg[0];
#pragma unroll
        for (int row = 0; row < 16; row++) {
            run = fmaxf(run, v[row]);
            int dn = (row < 15) ? dsg[row + 1] : (has_n ? dsg[16] : -1);
            if (dcur != dn) {
                if (lane < 8)
                    atomicMax(&y8[(size_t)dcur * 8 + lane], enc(run + b2c));
                run = -INFINITY;
            }
            dcur = dn;
        }
        asm volatile("s_waitcnt lgkmcnt(0)" ::: "memory");

        src_n = src_nn;
        af0_c = af0_n; af1_c = af1_n;
#pragma unroll
        for (int r = 0; r < 4; r++) av_c[r] = av_n[r];
    }
}

// ---------------- BatchNorm ----------------

__global__ __launch_bounds__(256)
void bn_stats(const unsigned* __restrict__ yk, float* __restrict__ st) {
    const int tid = threadIdx.x;
    const int ch = tid & 63, grp = tid >> 6;
    float s = 0, qq = 0;
    for (int n = blockIdx.x * 4 + grp; n < NN; n += gridDim.x * 4) {
        float v = dec(yk[(size_t)n * 64 + ch]);
        s += v;
        qq = fmaf(v, v, qq);
    }
    __shared__ float ls[256], lq[256];
    ls[tid] = s; lq[tid] = qq;
    __syncthreads();
    if (tid < 64) {
        s  = ls[tid] + ls[tid + 64] + ls[tid + 128] + ls[tid + 192];
        qq = lq[tid] + lq[tid + 64] + lq[tid + 128] + lq[tid + 192];
        atomicAdd(&st[ch], s);
        atomicAdd(&st[64 + ch], qq);
    }
}

// normalize, emit bf16 for the next layer, and re-zero y for the next layer's
// atomicMax accumulation (saves a separate 12.8 MB memset dispatch).
__global__ __launch_bounds__(256)
void bn_apply(unsigned* __restrict__ yk, const float* __restrict__ st,
              const float* __restrict__ g, const float* __restrict__ be,
              unsigned short* __restrict__ xbout) {
    int idx = blockIdx.x * 256 + threadIdx.x;
    if (idx >= NN * 64) return;
    int ch = idx & 63;
    float mu  = st[ch] * (1.0f / NN);
    float var = st[64 + ch] * (1.0f / NN) - mu * mu;
    float sc  = rsqrtf(var + 1e-5f) * g[ch];
    float v = (dec(yk[idx]) - mu) * sc + be[ch];
    xbout[idx] = (unsigned short)f2bf(v);
    yk[idx] = 0u;                                  // reset for next layer
}

__global__ __launch_bounds__(256)
void decode_out(const unsigned* __restrict__ y8, float* __restrict__ out) {
    int idx = blockIdx.x * 256 + threadIdx.x;
    if (idx < NN * 8) out[idx] = dec(y8[idx]);
}

// ---------------- launch ----------------

extern "C" void kernel_launch(void* const* d_in, const int* in_sizes, int n_in,
                              void* d_out, int out_size, void* d_ws, size_t ws_size,
                              hipStream_t stream) {
    const float* x0 = (const float*)d_in[0];
    const int*   ei = (const int*)d_in[1];
    const float* w1[4] = {(const float*)d_in[3],  (const float*)d_in[9],
                          (const float*)d_in[15], (const float*)d_in[21]};
    const float* b1[4] = {(const float*)d_in[4],  (const float*)d_in[10],
                          (const float*)d_in[16], (const float*)d_in[22]};
    const float* w2[4] = {(const float*)d_in[5],  (const float*)d_in[11],
                          (const float*)d_in[17], (const float*)d_in[23]};
    const float* b2[4] = {(const float*)d_in[6],  (const float*)d_in[12],
                          (const float*)d_in[18], (const float*)d_in[24]};
    const float* gg[3] = {(const float*)d_in[7],  (const float*)d_in[13],
                          (const float*)d_in[19]};
    const float* be[3] = {(const float*)d_in[8],  (const float*)d_in[14],
                          (const float*)d_in[20]};

    char* p = (char*)d_ws;
    auto alloc = [&](size_t bytes) -> char* {
        char* r = p;
        p += (bytes + 255) & ~(size_t)255;
        return r;
    };
    int*      cnt     = (int*)alloc((size_t)NN * 4);
    int*      part    = (int*)alloc((size_t)NBS * 4);
    int*      row_off = (int*)alloc((size_t)(NN + 1) * 4);
    int*      cur     = (int*)alloc((size_t)NN * 4);
    int*      csr_s   = (int*)alloc((size_t)EE * 4);
    int*      csr_d   = (int*)alloc((size_t)EE * 4);
    float*    st      = (float*)alloc(3 * 128 * 4);
    float*    a0      = (float*)alloc((size_t)NN * 64 * 4);   // reused for a0_8
    unsigned* y       = (unsigned*)alloc((size_t)NN * 64 * 4);
    unsigned* y8      = (unsigned*)alloc((size_t)NN * 8 * 4);
    unsigned short* xb0 = (unsigned short*)alloc((size_t)NN * 64 * 2); // also xbB
    unsigned short* xbA = (unsigned short*)alloc((size_t)NN * 64 * 2);
    unsigned short* xbB = xb0;

    hipMemsetAsync(cnt, 0, (size_t)NN * 4, stream);
    hipMemsetAsync(st, 0, 3 * 128 * 4, stream);
    hipMemsetAsync(y, 0, (size_t)NN * 64 * 4, stream);   // layer 0 only;
                                                         // bn_apply re-zeros after

    count_k<<<(EE + 255) / 256, 256, 0, stream>>>(ei, cnt);
    scan_part<<<NBS, 256, 0, stream>>>(cnt, part);
    scan_top<<<1, 256, 0, stream>>>(part);
    scan_fin<<<NBS, 256, 0, stream>>>(cnt, part, row_off, cur);
    scatter_k<<<(EE + 255) / 256, 256, 0, stream>>>(ei, cur, csr_s, csr_d);
    cvt_bf16<<<(NN * 64 + 255) / 256, 256, 0, stream>>>(x0, xb0, NN * 64);

    const int NBA = 256;
    const int NWA = NBA * 4;

    const unsigned short* xin[3] = {xb0, xbA, xbB};
    unsigned short* xout[3] = {xbA, xbB, xbA};
    for (int l = 0; l < 3; l++) {
        a0_mfma<<<NBA, 256, 0, stream>>>(xin[l], w1[l], b1[l], a0, NWA);
        edge_mfma64<<<NBLK, 256, 0, stream>>>(xin[l], a0, w1[l], w2[l], b2[l],
                                              csr_s, csr_d, y);
        bn_stats<<<256, 256, 0, stream>>>(y, st + 128 * l);
        bn_apply<<<(NN * 64 + 255) / 256, 256, 0, stream>>>(y, st + 128 * l,
                                                            gg[l], be[l], xout[l]);
    }

    // layer 3: xbA -> d_out [N,8]
    a0_mfma8<<<NBA, 256, 0, stream>>>(xbA, w1[3], b1[3], a0, NWA);
    hipMemsetAsync(y8, 0, (size_t)NN * 8 * 4, stream);
    edge_mfma16<<<NBLK, 256, 0, stream>>>(xbA, a0, w1[3], w2[3], b2[3],
                                          csr_s, csr_d, y8);
    decode_out<<<(NN * 8 + 255) / 256, 256, 0, stream>>>(y8, (float*)d_out);
}